// Round 3
// baseline (290.771 us; speedup 1.0000x reference)
//
#include <hip/hip_runtime.h>

#define Bc 8
#define Tc 4096
#define Dc 768
#define Hc 12
#define HDc 64
#define Kc 32
#define TD3 2304
#define WQKV_F (TD3 * Dc)          // 1,769,472 floats
#define WALL_F ((TD3 + Dc) * Dc)   // 2,359,296 floats (wqkv + wout)
#define SB_F (Bc * Tc * Kc)        // 1,048,576 floats
#define XS_F (Bc * Kc * Dc)        //   196,608 floats

typedef __attribute__((ext_vector_type(8))) short short8;
typedef __attribute__((ext_vector_type(4))) short short4v;
typedef __attribute__((ext_vector_type(4))) float float4v;

__device__ __forceinline__ float bf2f(unsigned short u) {
    unsigned v = ((unsigned)u) << 16;
    return __builtin_bit_cast(float, v);
}
__device__ __forceinline__ unsigned short f2bf(float f) {
    unsigned u = __builtin_bit_cast(unsigned, f);
    u += 0x7FFFu + ((u >> 16) & 1u);   // RNE
    return (unsigned short)(u >> 16);
}

// split 8 fp32 into bf16 hi + bf16 lo fragments (hi+lo ~ fp32 precision)
__device__ __forceinline__ void split8(const float* p, short8& hi, short8& lo) {
#pragma unroll
    for (int i = 0; i < 8; ++i) {
        unsigned short h = f2bf(p[i]);
        hi[i] = (short)h;
        lo[i] = (short)f2bf(p[i] - bf2f(h));
    }
}
__device__ __forceinline__ void split4(const float4v v, short4v& h, short4v& l) {
#pragma unroll
    for (int q = 0; q < 4; ++q) {
        unsigned short hb = f2bf(v[q]);
        h[q] = (short)hb;
        l[q] = (short)f2bf(v[q] - bf2f(hb));
    }
}

// ---------------------------------------------------------------------------
// kconv: blocks [0,2304): wqkv+wout fp32 -> bf16 hi/lo planes (streaming).
// blocks [2304,2560): sb 128t x 32k tile -> row-major planes (coalesced) AND
// LDS-transposed sbT[b][k][t] planes with 16B coalesced short8 stores.
// ---------------------------------------------------------------------------
__global__ __launch_bounds__(256) void kconv(const float* __restrict__ wqkv,
                                             const float* __restrict__ wout,
                                             const float* __restrict__ sb,
                                             short* __restrict__ w_hi, short* __restrict__ w_lo,
                                             short* __restrict__ sb_hi, short* __restrict__ sb_lo,
                                             short* __restrict__ sbT_hi, short* __restrict__ sbT_lo) {
    __shared__ float tile[128][33];    // +1 pad: conflict-free column gather
    int bid = blockIdx.x, tid = threadIdx.x;

    if (bid < 2304) {
        int i = (bid * 256 + tid) * 4;
        const float* src = (i < WQKV_F) ? (wqkv + i) : (wout + (i - WQKV_F));
        float4v v = *(const float4v*)src;
        short4v h, l;
        split4(v, h, l);
        *(short4v*)(w_hi + i) = h;
        *(short4v*)(w_lo + i) = l;
        return;
    }

    int sbi = bid - 2304;              // 0..255 = 8b x 32 t-tiles of 128
    int b  = sbi >> 5;
    int tt = sbi & 31;
    size_t base = ((size_t)b * Tc + tt * 128) * Kc;

#pragma unroll
    for (int p = 0; p < 4; ++p) {
        int f4  = tid + p * 256;       // 0..1023
        int row = f4 >> 3, c4 = f4 & 7;
        size_t o = base + (size_t)row * Kc + c4 * 4;
        float4v v = *(const float4v*)(sb + o);
        short4v h, l;
        split4(v, h, l);
        *(short4v*)(sb_hi + o) = h;
        *(short4v*)(sb_lo + o) = l;
#pragma unroll
        for (int q = 0; q < 4; ++q) tile[row][c4 * 4 + q] = v[q];
    }
    __syncthreads();

    size_t tb = (size_t)b * Kc * Tc + tt * 128;
#pragma unroll
    for (int p = 0; p < 2; ++p) {
        int u  = tid + p * 256;        // 0..511 = 32k x 16 t-segments
        int k  = u >> 4, ts = u & 15;
        float av[8];
#pragma unroll
        for (int j = 0; j < 8; ++j) av[j] = tile[ts * 8 + j][k];
        short8 h, l;
        split8(av, h, l);
        *(short8*)(sbT_hi + tb + (size_t)k * Tc + ts * 8) = h;
        *(short8*)(sbT_lo + tb + (size_t)k * Tc + ts * 8) = l;
    }
}

// ---------------------------------------------------------------------------
// K1: pb[tc][b][kk][d] = sum_{t in 256-chunk tc} sb[b,t,kk] * x[b,t,d]
// Grid 1536 = 8b x 16tc x 12dt (64-col d tiles); 6 blocks/CU for latency
// hiding. A = sbT bf16 planes (16B loads); B = x scalar gathers + one split.
// Each wave owns one 16-col n-tile; acc = 2 m-tiles (kk 0..31).
// ---------------------------------------------------------------------------
__global__ __launch_bounds__(256) void k1_xspec(const float* __restrict__ x,
                                                const short* __restrict__ sbT_hi,
                                                const short* __restrict__ sbT_lo,
                                                float* __restrict__ pb) {
    int tid  = threadIdx.x;
    int w    = tid >> 6;
    int lane = tid & 63;
    int col  = lane & 15;
    int quad = lane >> 4;

    int bid = blockIdx.x;              // 1536 = 8b x 16tc x 12dt
    int b  = bid / 192;
    int r2 = bid % 192;
    int tc = r2 / 12;
    int dt = r2 % 12;
    int nc = dt * 64 + w * 16 + col;
    size_t bT = (size_t)b * Tc + (size_t)tc * 256;

    float4v acc[2];
    acc[0] = (float4v){0.f, 0.f, 0.f, 0.f};
    acc[1] = (float4v){0.f, 0.f, 0.f, 0.f};

#pragma unroll 2
    for (int ks = 0; ks < 8; ++ks) {
        int t8 = tc * 256 + ks * 32 + quad * 8;
        short8 ah[2], al[2];
#pragma unroll
        for (int mi = 0; mi < 2; ++mi) {
            size_t ai = ((size_t)b * Kc + mi * 16 + col) * Tc + t8;
            ah[mi] = *(const short8*)(sbT_hi + ai);
            al[mi] = *(const short8*)(sbT_lo + ai);
        }
        float bv[8];
#pragma unroll
        for (int j = 0; j < 8; ++j)
            bv[j] = x[(bT + ks * 32 + quad * 8 + j) * Dc + nc];
        short8 bh, bl;
        split8(bv, bh, bl);
#pragma unroll
        for (int mi = 0; mi < 2; ++mi) {
            acc[mi] = __builtin_amdgcn_mfma_f32_16x16x32_bf16(ah[mi], bh, acc[mi], 0, 0, 0);
            acc[mi] = __builtin_amdgcn_mfma_f32_16x16x32_bf16(al[mi], bh, acc[mi], 0, 0, 0);
            acc[mi] = __builtin_amdgcn_mfma_f32_16x16x32_bf16(ah[mi], bl, acc[mi], 0, 0, 0);
        }
    }

    // exclusive write to pb[tc]
    float* pbp = pb + (size_t)tc * XS_F;
#pragma unroll
    for (int mi = 0; mi < 2; ++mi)
#pragma unroll
        for (int r = 0; r < 4; ++r) {
            int kk = mi * 16 + quad * 4 + r;
            pbp[((size_t)(b * Kc + kk)) * Dc + nc] = acc[mi][r];
        }
}

// reduce 16 partials -> xs bf16 hi/lo planes (unchanged)
__global__ __launch_bounds__(256) void k1r_reduce(const float* __restrict__ pb,
                                                  short* __restrict__ xs_hi,
                                                  short* __restrict__ xs_lo) {
    int i = (blockIdx.x * 256 + threadIdx.x) * 4;   // 192 blocks -> 196608 floats
    float4v s = (float4v){0.f, 0.f, 0.f, 0.f};
#pragma unroll
    for (int p = 0; p < 16; ++p) {
        float4v v = *(const float4v*)(pb + (size_t)p * XS_F + i);
#pragma unroll
        for (int q = 0; q < 4; ++q) s[q] += v[q];
    }
    short4v h, l;
    split4(s, h, l);
    *(short4v*)(xs_hi + i) = h;
    *(short4v*)(xs_lo + i) = l;
}

// ---------------------------------------------------------------------------
// K2: c1[r, j] = sum_c xs[r, c] * wqkv[j, c] — pure-MFMA bf16-plane GEMM.
// Grid 576 = 16mb x 36nb, wave tile 16x16 (2.25 blocks/CU).
// ---------------------------------------------------------------------------
__global__ __launch_bounds__(256) void k2_qkv(const short* __restrict__ xs_hi,
                                              const short* __restrict__ xs_lo,
                                              const short* __restrict__ w_hi,
                                              const short* __restrict__ w_lo,
                                              float* __restrict__ c1) {
    int lane = threadIdx.x & 63;
    int w    = threadIdx.x >> 6;
    int m    = lane & 15, quad = lane >> 4;
    int mb = blockIdx.x & 15;
    int nb = blockIdx.x >> 4;
    int m0 = mb * 16;
    int n0 = nb * 64 + w * 16;

    const short* ahp = xs_hi + (size_t)(m0 + m) * Dc + quad * 8;
    const short* alp = xs_lo + (size_t)(m0 + m) * Dc + quad * 8;
    const short* bhp = w_hi + (size_t)(n0 + m) * Dc + quad * 8;
    const short* blp = w_lo + (size_t)(n0 + m) * Dc + quad * 8;

    float4v acc = (float4v){0.f, 0.f, 0.f, 0.f};
#pragma unroll 4
    for (int s = 0; s < 24; ++s) {
        short8 ah = *(const short8*)(ahp + s * 32);
        short8 al = *(const short8*)(alp + s * 32);
        short8 bh = *(const short8*)(bhp + s * 32);
        short8 bl = *(const short8*)(blp + s * 32);
        acc = __builtin_amdgcn_mfma_f32_16x16x32_bf16(ah, bh, acc, 0, 0, 0);
        acc = __builtin_amdgcn_mfma_f32_16x16x32_bf16(al, bh, acc, 0, 0, 0);
        acc = __builtin_amdgcn_mfma_f32_16x16x32_bf16(ah, bl, acc, 0, 0, 0);
    }
    float* cp = c1 + (size_t)(m0 + quad * 4) * TD3 + n0 + m;
#pragma unroll
    for (int r = 0; r < 4; ++r) cp[(size_t)r * TD3] = acc[r];
}

// ---------------------------------------------------------------------------
// K3: attn dot (q.k)/8 * sigmoid(filter) -> FHN, then scale this (b,h,k)'s
// 64-col v_spec segment and emit av bf16 hi/lo planes. (unchanged)
// ---------------------------------------------------------------------------
__global__ __launch_bounds__(64) void k3_fhn(const float* __restrict__ c1,
                                             const float* __restrict__ sfilt,
                                             short* __restrict__ av_hi,
                                             short* __restrict__ av_lo) {
    int idx = blockIdx.x * 64 + threadIdx.x;
    int kk = idx & 31;
    int bh = idx >> 5;
    int h  = bh % Hc;
    int r  = (bh / Hc) * Kc + kk;

    const float* qp = c1 + (size_t)r * TD3 + h * HDc;
    const float* kp = qp + Dc;
    float s = 0.f;
#pragma unroll
    for (int dd = 0; dd < HDc; ++dd) s = fmaf(qp[dd], kp[dd], s);
    s *= 0.125f;

    float filt = 1.f / (1.f + __expf(-sfilt[h * 32 + kk]));
    s *= filt;

    float as    = fabsf(s);
    float scale = fmaxf(as, 1e-6f);
    float sn    = s / scale;
    float gate  = 1.f / (1.f + __expf(-(as - 0.5f) * 10.f));
    float I     = sn * (0.1f + 0.9f * gate);
    const float alpha = 0.08f;
    const float denom = 1.064f;
    float v = 0.f, w = 0.f;
#pragma unroll
    for (int it = 0; it < 2; ++it) {
        float dv = v - (v * v * v) / 3.f - w + I;
        float vn = v + dv;
        float wn = (w + (vn + 0.7f) * alpha) / denom;
        v = fminf(fmaxf(vn, -3.f), 3.f);
        w = fminf(fmaxf(wn, -3.f), 3.f);
    }
    float fv = v * scale;

    const float* vp = c1 + (size_t)r * TD3 + 2 * Dc + h * HDc;
    short* ohp = av_hi + (size_t)r * Dc + h * HDc;
    short* olp = av_lo + (size_t)r * Dc + h * HDc;
#pragma unroll
    for (int i = 0; i < 16; ++i) {
        float4v vv = *(const float4v*)(vp + i * 4);
#pragma unroll
        for (int q = 0; q < 4; ++q) vv[q] *= fv;
        short4v hv, lv;
        split4(vv, hv, lv);
        *(short4v*)(ohp + i * 4) = hv;
        *(short4v*)(olp + i * 4) = lv;
    }
}

// ---------------------------------------------------------------------------
// K4: proj[r,e] = sum_c av[r,c] * wout[e,c] — pure-MFMA bf16-plane GEMM.
// Writes proj TRANSPOSED bf16 planes pT[e][r]. (unchanged)
// ---------------------------------------------------------------------------
__global__ __launch_bounds__(256) void k4_proj(const short* __restrict__ av_hi,
                                               const short* __restrict__ av_lo,
                                               const short* __restrict__ wo_hi,
                                               const short* __restrict__ wo_lo,
                                               short* __restrict__ pT_hi,
                                               short* __restrict__ pT_lo) {
    int wave = blockIdx.x * 4 + (threadIdx.x >> 6);
    int lane = threadIdx.x & 63;
    int mb = wave & 15;
    int nt = wave >> 4;                // 48 n-tiles
    int m0 = mb * 16, n0 = nt * 16;
    int m = lane & 15, quad = lane >> 4;

    const short* ahp = av_hi + (size_t)(m0 + m) * Dc + quad * 8;
    const short* alp = av_lo + (size_t)(m0 + m) * Dc + quad * 8;
    const short* bhp = wo_hi + (size_t)(n0 + m) * Dc + quad * 8;
    const short* blp = wo_lo + (size_t)(n0 + m) * Dc + quad * 8;

    float4v acc = (float4v){0.f, 0.f, 0.f, 0.f};
#pragma unroll 4
    for (int s = 0; s < 24; ++s) {
        short8 ah = *(const short8*)(ahp + s * 32);
        short8 al = *(const short8*)(alp + s * 32);
        short8 bh = *(const short8*)(bhp + s * 32);
        short8 bl = *(const short8*)(blp + s * 32);
        acc = __builtin_amdgcn_mfma_f32_16x16x32_bf16(ah, bh, acc, 0, 0, 0);
        acc = __builtin_amdgcn_mfma_f32_16x16x32_bf16(al, bh, acc, 0, 0, 0);
        acc = __builtin_amdgcn_mfma_f32_16x16x32_bf16(ah, bl, acc, 0, 0, 0);
    }
    short4v hv, lv;
    split4(acc, hv, lv);
    size_t o = (size_t)(n0 + m) * (Bc * Kc) + m0 + quad * 4;   // pT[e][r]
    *(short4v*)(pT_hi + o) = hv;
    *(short4v*)(pT_lo + o) = lv;
}

// ---------------------------------------------------------------------------
// K5: out[b,t,e] = sum_k sb[b,t,k] * proj[b,k,e] — plane-only, LDS-free.
// (unchanged)
// ---------------------------------------------------------------------------
__global__ __launch_bounds__(256) void k5_out(const short* __restrict__ pT_hi,
                                              const short* __restrict__ pT_lo,
                                              const short* __restrict__ sb_hi,
                                              const short* __restrict__ sb_lo,
                                              float* __restrict__ out) {
    int tid  = threadIdx.x;
    int w    = tid >> 6;
    int lane = tid & 63;
    int col  = lane & 15;
    int quad = lane >> 4;

    int bid = blockIdx.x;
    int b  = bid >> 8;
    int tt = (bid >> 2) & 63;
    int et = bid & 3;
    int t0 = tt * 64 + w * 16;
    int e0 = et * 192;

    size_t ao = ((size_t)b * Tc + t0 + col) * Kc + quad * 8;
    short8 ah = *(const short8*)(sb_hi + ao);
    short8 al = *(const short8*)(sb_lo + ao);

    float4v acc[12];
#pragma unroll
    for (int ni = 0; ni < 12; ++ni) acc[ni] = (float4v){0.f, 0.f, 0.f, 0.f};

#pragma unroll
    for (int ni = 0; ni < 12; ++ni) {
        size_t bo = (size_t)(e0 + ni * 16 + col) * (Bc * Kc) + b * 32 + quad * 8;
        short8 bh = *(const short8*)(pT_hi + bo);
        short8 bl = *(const short8*)(pT_lo + bo);
        acc[ni] = __builtin_amdgcn_mfma_f32_16x16x32_bf16(ah, bh, acc[ni], 0, 0, 0);
        acc[ni] = __builtin_amdgcn_mfma_f32_16x16x32_bf16(al, bh, acc[ni], 0, 0, 0);
        acc[ni] = __builtin_amdgcn_mfma_f32_16x16x32_bf16(ah, bl, acc[ni], 0, 0, 0);
    }

    float* op = out + ((size_t)b * Tc + t0 + quad * 4) * Dc + e0 + col;
#pragma unroll
    for (int ni = 0; ni < 12; ++ni)
#pragma unroll
        for (int r = 0; r < 4; ++r)
            op[(size_t)r * Dc + ni * 16] = acc[ni][r];
}

extern "C" void kernel_launch(void* const* d_in, const int* in_sizes, int n_in,
                              void* d_out, int out_size, void* d_ws, size_t ws_size,
                              hipStream_t stream) {
    const float* x     = (const float*)d_in[0];
    const float* sb    = (const float*)d_in[1];
    const float* wqkv  = (const float*)d_in[2];
    const float* wout  = (const float*)d_in[3];
    const float* sfilt = (const float*)d_in[4];
    float* out = (float*)d_out;

    // workspace layout (~43 MB, no aliasing):
    float* pb    = (float*)d_ws;                        // 3,145,728 f (12.6 MB)
    short* w_hi  = (short*)(pb + (size_t)16 * XS_F);    // 2,359,296 sh
    short* w_lo  = w_hi + (size_t)WALL_F;               // 2,359,296 sh
    short* xs_hi = w_lo + (size_t)WALL_F;               //   196,608 sh
    short* xs_lo = xs_hi + (size_t)XS_F;                //   196,608 sh
    float* c1    = (float*)(xs_lo + (size_t)XS_F);      //   589,824 f
    short* av_hi = (short*)(c1 + (size_t)Bc * Kc * TD3);
    short* av_lo = av_hi + (size_t)XS_F;
    short* pT_hi = av_lo + (size_t)XS_F;
    short* pT_lo = pT_hi + (size_t)XS_F;
    short* sb_hi = pT_lo + (size_t)XS_F;
    short* sb_lo = sb_hi + (size_t)SB_F;
    short* sbT_hi = sb_lo + (size_t)SB_F;
    short* sbT_lo = sbT_hi + (size_t)SB_F;

    const short* wo_hi = w_hi + (size_t)WQKV_F;
    const short* wo_lo = w_lo + (size_t)WQKV_F;

    hipLaunchKernelGGL(kconv,      dim3(2560), dim3(256), 0, stream, wqkv, wout, sb,
                       w_hi, w_lo, sb_hi, sb_lo, sbT_hi, sbT_lo);
    hipLaunchKernelGGL(k1_xspec,   dim3(1536), dim3(256), 0, stream, x, sbT_hi, sbT_lo, pb);
    hipLaunchKernelGGL(k1r_reduce, dim3(192),  dim3(256), 0, stream, pb, xs_hi, xs_lo);
    hipLaunchKernelGGL(k2_qkv,     dim3(576),  dim3(256), 0, stream, xs_hi, xs_lo, w_hi, w_lo, c1);
    hipLaunchKernelGGL(k3_fhn,     dim3(48),   dim3(64),  0, stream, c1, sfilt, av_hi, av_lo);
    hipLaunchKernelGGL(k4_proj,    dim3(192),  dim3(256), 0, stream, av_hi, av_lo, wo_hi, wo_lo, pT_hi, pT_lo);
    hipLaunchKernelGGL(k5_out,     dim3(2048), dim3(256), 0, stream, pT_hi, pT_lo, sb_hi, sb_lo, out);
}

// Round 5
// 258.976 us; speedup vs baseline: 1.1228x; 1.1228x over previous
//
#include <hip/hip_runtime.h>

#define Bc 8
#define Tc 4096
#define Dc 768
#define Hc 12
#define HDc 64
#define Kc 32
#define TD3 2304
#define WQKV_F (TD3 * Dc)          // 1,769,472 floats
#define WALL_F ((TD3 + Dc) * Dc)   // 2,359,296 floats (wqkv + wout)
#define XS_F (Bc * Kc * Dc)        //   196,608 floats

typedef __attribute__((ext_vector_type(8))) short short8;
typedef __attribute__((ext_vector_type(4))) short short4v;
typedef __attribute__((ext_vector_type(4))) float float4v;

__device__ __forceinline__ float bf2f(unsigned short u) {
    unsigned v = ((unsigned)u) << 16;
    return __builtin_bit_cast(float, v);
}
__device__ __forceinline__ unsigned short f2bf(float f) {
    unsigned u = __builtin_bit_cast(unsigned, f);
    u += 0x7FFFu + ((u >> 16) & 1u);   // RNE
    return (unsigned short)(u >> 16);
}
__device__ __forceinline__ void split8(const float* p, short8& hi, short8& lo) {
#pragma unroll
    for (int i = 0; i < 8; ++i) {
        unsigned short h = f2bf(p[i]);
        hi[i] = (short)h;
        lo[i] = (short)f2bf(p[i] - bf2f(h));
    }
}
__device__ __forceinline__ void split4(const float4v v, short4v& h, short4v& l) {
#pragma unroll
    for (int q = 0; q < 4; ++q) {
        unsigned short hb = f2bf(v[q]);
        h[q] = (short)hb;
        l[q] = (short)f2bf(v[q] - bf2f(hb));
    }
}

// ---------------------------------------------------------------------------
// L1 (fused): bids [0,512) = k1 spectral GEMM (R1-exact body, all blocks
// resident immediately); bids [512,2816) = weight fp32 -> bf16 hi/lo plane
// conversion streaming on the CUs k1 leaves idle. No data dependency between
// the halves. One launch replaces two and gives k1 latency-hiding co-tenants.
// ---------------------------------------------------------------------------
__global__ __launch_bounds__(256) void k1_fused(const float* __restrict__ x,
                                                const float* __restrict__ sb,
                                                const float* __restrict__ wqkv,
                                                const float* __restrict__ wout,
                                                float* __restrict__ pb,
                                                short* __restrict__ w_hi,
                                                short* __restrict__ w_lo) {
    __shared__ float xt[32 * 193];
    __shared__ float st[32 * 33];

    int tid = threadIdx.x;
    int bid = blockIdx.x;

    if (bid >= 512) {                  // ---- weight conversion half
        int i = ((bid - 512) * 256 + tid) * 4;
        const float* src = (i < WQKV_F) ? (wqkv + i) : (wout + (i - WQKV_F));
        float4v v = *(const float4v*)src;
        short4v h, l;
        split4(v, h, l);
        *(short4v*)(w_hi + i) = h;
        *(short4v*)(w_lo + i) = l;
        return;
    }

    // ---- k1 half (R1-exact)
    int w    = tid >> 6;
    int lane = tid & 63;
    int col  = lane & 15;
    int quad = lane >> 4;

    int b  = bid >> 6;
    int dt = (bid >> 4) & 3;
    int tc = bid & 15;
    int d0 = dt * 192;
    size_t bT = (size_t)b * Tc + (size_t)tc * 256;

    float4v acc[2][3];
#pragma unroll
    for (int mi = 0; mi < 2; ++mi)
#pragma unroll
        for (int ni = 0; ni < 3; ++ni) acc[mi][ni] = (float4v){0.f, 0.f, 0.f, 0.f};

    for (int ks = 0; ks < 8; ++ks) {
        __syncthreads();
#pragma unroll
        for (int i = 0; i < 6; ++i) {
            int f4  = tid + i * 256;
            int row = f4 / 48, c4 = f4 % 48;
            float4v v = *(const float4v*)&x[(bT + ks * 32 + row) * Dc + d0 + c4 * 4];
#pragma unroll
            for (int q = 0; q < 4; ++q) xt[row * 193 + c4 * 4 + q] = v[q];
        }
        {
            int row = tid >> 3, c4 = tid & 7;
            float4v v = *(const float4v*)&sb[(bT + ks * 32 + row) * Kc + c4 * 4];
#pragma unroll
            for (int q = 0; q < 4; ++q) st[row * 33 + c4 * 4 + q] = v[q];
        }
        __syncthreads();

        short8 ah[2], al[2];
#pragma unroll
        for (int mi = 0; mi < 2; ++mi) {
            float av[8];
#pragma unroll
            for (int j = 0; j < 8; ++j)
                av[j] = st[(quad * 8 + j) * 33 + mi * 16 + col];
            split8(av, ah[mi], al[mi]);
        }
#pragma unroll
        for (int ni = 0; ni < 3; ++ni) {
            int nc = (w * 3 + ni) * 16 + col;
            float bv[8];
#pragma unroll
            for (int j = 0; j < 8; ++j)
                bv[j] = xt[(quad * 8 + j) * 193 + nc];
            short8 bh, bl;
            split8(bv, bh, bl);
#pragma unroll
            for (int mi = 0; mi < 2; ++mi) {
                acc[mi][ni] = __builtin_amdgcn_mfma_f32_16x16x32_bf16(ah[mi], bh, acc[mi][ni], 0, 0, 0);
                acc[mi][ni] = __builtin_amdgcn_mfma_f32_16x16x32_bf16(al[mi], bh, acc[mi][ni], 0, 0, 0);
                acc[mi][ni] = __builtin_amdgcn_mfma_f32_16x16x32_bf16(ah[mi], bl, acc[mi][ni], 0, 0, 0);
            }
        }
    }

    float* pbp = pb + (size_t)tc * XS_F;
#pragma unroll
    for (int mi = 0; mi < 2; ++mi)
#pragma unroll
        for (int ni = 0; ni < 3; ++ni)
#pragma unroll
            for (int r = 0; r < 4; ++r) {
                int kk = mi * 16 + quad * 4 + r;
                int dd = d0 + (w * 3 + ni) * 16 + col;
                pbp[((size_t)(b * Kc + kk)) * Dc + dd] = acc[mi][ni][r];
            }
}

// reduce 16 partials -> xs bf16 hi/lo planes (R1-exact)
__global__ __launch_bounds__(256) void k1r_reduce(const float* __restrict__ pb,
                                                  short* __restrict__ xs_hi,
                                                  short* __restrict__ xs_lo) {
    int i = (blockIdx.x * 256 + threadIdx.x) * 4;
    float4v s = (float4v){0.f, 0.f, 0.f, 0.f};
#pragma unroll
    for (int p = 0; p < 16; ++p) {
        float4v v = *(const float4v*)(pb + (size_t)p * XS_F + i);
#pragma unroll
        for (int q = 0; q < 4; ++q) s[q] += v[q];
    }
    short4v h, l;
    split4(s, h, l);
    *(short4v*)(xs_hi + i) = h;
    *(short4v*)(xs_lo + i) = l;
}

// K2: pure-plane GEMM (R1-exact: grid 288, wave tile 32x16)
__global__ __launch_bounds__(256) void k2_qkv(const short* __restrict__ xs_hi,
                                              const short* __restrict__ xs_lo,
                                              const short* __restrict__ w_hi,
                                              const short* __restrict__ w_lo,
                                              float* __restrict__ c1) {
    int lane = threadIdx.x & 63;
    int w    = threadIdx.x >> 6;
    int m    = lane & 15, quad = lane >> 4;
    int mb = blockIdx.x & 7;
    int nb = blockIdx.x >> 3;
    int m0 = mb * 32;
    int n0 = nb * 64 + w * 16;

    const short* a0h = xs_hi + (size_t)(m0 + m) * Dc + quad * 8;
    const short* a0l = xs_lo + (size_t)(m0 + m) * Dc + quad * 8;
    const short* a1h = a0h + (size_t)16 * Dc;
    const short* a1l = a0l + (size_t)16 * Dc;
    const short* bhp = w_hi + (size_t)(n0 + m) * Dc + quad * 8;
    const short* blp = w_lo + (size_t)(n0 + m) * Dc + quad * 8;

    float4v acc0 = (float4v){0.f, 0.f, 0.f, 0.f};
    float4v acc1 = (float4v){0.f, 0.f, 0.f, 0.f};
#pragma unroll 4
    for (int s = 0; s < 24; ++s) {
        short8 bh = *(const short8*)(bhp + s * 32);
        short8 bl = *(const short8*)(blp + s * 32);
        short8 h0 = *(const short8*)(a0h + s * 32);
        short8 l0 = *(const short8*)(a0l + s * 32);
        short8 h1 = *(const short8*)(a1h + s * 32);
        short8 l1 = *(const short8*)(a1l + s * 32);
        acc0 = __builtin_amdgcn_mfma_f32_16x16x32_bf16(h0, bh, acc0, 0, 0, 0);
        acc0 = __builtin_amdgcn_mfma_f32_16x16x32_bf16(l0, bh, acc0, 0, 0, 0);
        acc0 = __builtin_amdgcn_mfma_f32_16x16x32_bf16(h0, bl, acc0, 0, 0, 0);
        acc1 = __builtin_amdgcn_mfma_f32_16x16x32_bf16(h1, bh, acc1, 0, 0, 0);
        acc1 = __builtin_amdgcn_mfma_f32_16x16x32_bf16(l1, bh, acc1, 0, 0, 0);
        acc1 = __builtin_amdgcn_mfma_f32_16x16x32_bf16(h1, bl, acc1, 0, 0, 0);
    }
    float* cp0 = c1 + (size_t)(m0 + quad * 4) * TD3 + n0 + m;
    float* cp1 = cp0 + (size_t)16 * TD3;
#pragma unroll
    for (int r = 0; r < 4; ++r) {
        cp0[(size_t)r * TD3] = acc0[r];
        cp1[(size_t)r * TD3] = acc1[r];
    }
}

// K3: FHN (R1-exact: grid 12x256, writes fhn[] fp32)
__global__ __launch_bounds__(256) void k3_fhn(const float* __restrict__ c1,
                                              const float* __restrict__ sfilt,
                                              float* __restrict__ fhn) {
    int idx = blockIdx.x * 256 + threadIdx.x;
    if (idx >= Bc * Hc * Kc) return;
    int kk = idx & 31;
    int bh = idx >> 5;
    int h  = bh % Hc;
    int r  = (bh / Hc) * Kc + kk;

    const float* qp = c1 + (size_t)r * TD3 + h * HDc;
    const float* kp = qp + Dc;
    float s = 0.f;
#pragma unroll
    for (int dd = 0; dd < HDc; ++dd) s = fmaf(qp[dd], kp[dd], s);
    s *= 0.125f;

    float filt = 1.f / (1.f + __expf(-sfilt[h * 32 + kk]));
    s *= filt;

    float as    = fabsf(s);
    float scale = fmaxf(as, 1e-6f);
    float sn    = s / scale;
    float gate  = 1.f / (1.f + __expf(-(as - 0.5f) * 10.f));
    float I     = sn * (0.1f + 0.9f * gate);
    const float alpha = 0.08f;
    const float denom = 1.064f;
    float v = 0.f, w = 0.f;
#pragma unroll
    for (int it = 0; it < 2; ++it) {
        float dv = v - (v * v * v) / 3.f - w + I;
        float vn = v + dv;
        float wn = (w + (vn + 0.7f) * alpha) / denom;
        v = fminf(fmaxf(vn, -3.f), 3.f);
        w = fminf(fmaxf(wn, -3.f), 3.f);
    }
    fhn[idx] = v * scale;
}

// K4: proj GEMM (R1-exact: B planes, A = fhn-scaled c1 inline split, grid 192)
__global__ __launch_bounds__(256) void k4_proj(const float* __restrict__ c1,
                                               const float* __restrict__ fhn,
                                               const short* __restrict__ wo_hi,
                                               const short* __restrict__ wo_lo,
                                               float* __restrict__ proj) {
    int wave = blockIdx.x * 4 + (threadIdx.x >> 6);
    int lane = threadIdx.x & 63;
    int mb = wave & 15;
    int nt = wave >> 4;
    int m0 = mb * 16, n0 = nt * 16;
    int m = lane & 15, quad = lane >> 4;

    const short* bhp = wo_hi + (size_t)(n0 + m) * Dc + quad * 8;
    const short* blp = wo_lo + (size_t)(n0 + m) * Dc + quad * 8;

    int r = m0 + m;
    int b = r >> 5, kk = r & 31;
    const float* apx = c1 + (size_t)r * TD3 + 2 * Dc + quad * 8;
    const float* fp  = fhn + (size_t)b * Hc * Kc + kk;

    float4v acc = (float4v){0.f, 0.f, 0.f, 0.f};
#pragma unroll 4
    for (int s = 0; s < 24; ++s) {
        int h = (s * 32 + quad * 8) >> 6;
        float f = fp[h * Kc];
        float av[8];
#pragma unroll
        for (int i = 0; i < 8; ++i) av[i] = apx[s * 32 + i] * f;
        short8 ah, al;
        split8(av, ah, al);
        short8 bh = *(const short8*)(bhp + s * 32);
        short8 bl = *(const short8*)(blp + s * 32);
        acc = __builtin_amdgcn_mfma_f32_16x16x32_bf16(ah, bh, acc, 0, 0, 0);
        acc = __builtin_amdgcn_mfma_f32_16x16x32_bf16(al, bh, acc, 0, 0, 0);
        acc = __builtin_amdgcn_mfma_f32_16x16x32_bf16(ah, bl, acc, 0, 0, 0);
    }
    float* cp = proj + (size_t)(m0 + quad * 4) * Dc + n0 + m;
#pragma unroll
    for (int rr = 0; rr < 4; ++rr) cp[(size_t)rr * Dc] = acc[rr];
}

// K5: out GEMM (R1-exact: LDS proj tile, raw fp32 sb, grid 2048)
__global__ __launch_bounds__(256) void k5_out(const float* __restrict__ proj,
                                              const float* __restrict__ sb,
                                              float* __restrict__ out) {
    __shared__ float pt[32 * 193];

    int tid  = threadIdx.x;
    int w    = tid >> 6;
    int lane = tid & 63;
    int col  = lane & 15;
    int quad = lane >> 4;

    int bid = blockIdx.x;
    int b  = bid >> 8;
    int tt = (bid >> 2) & 63;
    int et = bid & 3;
    int t0 = tt * 64 + w * 16;
    int e0 = et * 192;

#pragma unroll
    for (int i = 0; i < 6; ++i) {
        int f4  = tid + i * 256;
        int row = f4 / 48, c4 = f4 % 48;
        float4v v = *(const float4v*)&proj[(size_t)b * Kc * Dc + (size_t)row * Dc + e0 + c4 * 4];
#pragma unroll
        for (int q = 0; q < 4; ++q) pt[row * 193 + c4 * 4 + q] = v[q];
    }

    const float* apx = sb + ((size_t)b * Tc + t0 + col) * Kc + quad * 8;
    short8 ah, al;
    split8(apx, ah, al);

    __syncthreads();

    float4v acc[12];
#pragma unroll
    for (int ni = 0; ni < 12; ++ni) acc[ni] = (float4v){0.f, 0.f, 0.f, 0.f};

#pragma unroll
    for (int ni = 0; ni < 12; ++ni) {
        float bv[8];
#pragma unroll
        for (int j = 0; j < 8; ++j)
            bv[j] = pt[(quad * 8 + j) * 193 + ni * 16 + col];
        short8 bh, bl;
        split8(bv, bh, bl);
        acc[ni] = __builtin_amdgcn_mfma_f32_16x16x32_bf16(ah, bh, acc[ni], 0, 0, 0);
        acc[ni] = __builtin_amdgcn_mfma_f32_16x16x32_bf16(al, bh, acc[ni], 0, 0, 0);
        acc[ni] = __builtin_amdgcn_mfma_f32_16x16x32_bf16(ah, bl, acc[ni], 0, 0, 0);
    }

    float* op = out + ((size_t)b * Tc + t0 + quad * 4) * Dc + e0 + col;
#pragma unroll
    for (int ni = 0; ni < 12; ++ni)
#pragma unroll
        for (int r = 0; r < 4; ++r)
            op[(size_t)r * Dc + ni * 16] = acc[ni][r];
}

extern "C" void kernel_launch(void* const* d_in, const int* in_sizes, int n_in,
                              void* d_out, int out_size, void* d_ws, size_t ws_size,
                              hipStream_t stream) {
    const float* x     = (const float*)d_in[0];
    const float* sb    = (const float*)d_in[1];
    const float* wqkv  = (const float*)d_in[2];
    const float* wout  = (const float*)d_in[3];
    const float* sfilt = (const float*)d_in[4];
    float* out = (float*)d_out;

    // workspace layout (R1-identical, ~26.7 MB)
    float* pb    = (float*)d_ws;                        // 16*XS_F f (12.6 MB)
    short* w_hi  = (short*)(pb + (size_t)16 * XS_F);    // WALL_F sh
    short* w_lo  = w_hi + (size_t)WALL_F;               // WALL_F sh
    short* xs_hi = w_lo + (size_t)WALL_F;               // XS_F sh
    short* xs_lo = xs_hi + (size_t)XS_F;                // XS_F sh
    float* c1    = (float*)(xs_lo + (size_t)XS_F);      // 589,824 f
    float* fhn   = c1 + (size_t)Bc * Kc * TD3;          // 3,072 f
    float* proj  = fhn + (size_t)Bc * Hc * Kc;          // XS_F f

    const short* wo_hi = w_hi + (size_t)WQKV_F;
    const short* wo_lo = w_lo + (size_t)WQKV_F;

    hipLaunchKernelGGL(k1_fused,   dim3(2816), dim3(256), 0, stream,
                       x, sb, wqkv, wout, pb, w_hi, w_lo);
    hipLaunchKernelGGL(k1r_reduce, dim3(192),  dim3(256), 0, stream, pb, xs_hi, xs_lo);
    hipLaunchKernelGGL(k2_qkv,     dim3(288),  dim3(256), 0, stream, xs_hi, xs_lo, w_hi, w_lo, c1);
    hipLaunchKernelGGL(k3_fhn,     dim3(12),   dim3(256), 0, stream, c1, sfilt, fhn);
    hipLaunchKernelGGL(k4_proj,    dim3(192),  dim3(256), 0, stream, c1, fhn, wo_hi, wo_lo, proj);
    hipLaunchKernelGGL(k5_out,     dim3(2048), dim3(256), 0, stream, proj, sb, out);
}